// Round 5
// baseline (135.174 us; speedup 1.0000x reference)
//
#include <hip/hip_runtime.h>

#define B 16
typedef float f32x4 __attribute__((ext_vector_type(4)));

// pw layout: .x = bit-packed indices (i0 | i1<<10 | i2<<20), .y/.z/.w = weights
__device__ __forceinline__ void unpack_pw(const f32x4 pw, int& i0, int& i1, int& i2) {
    unsigned p = __float_as_uint(pw[0]);
    i0 = p & 1023; i1 = (p >> 10) & 1023; i2 = p >> 20;
}

// ===================== fused 4-stage 3-NN + f0 copy =====================
// Blocks [0,1024): stage3; [1024,1280): stage2; [1280,1344): stage1;
// [1344,1360): stage0; [1360,1488): f0 -> out copy (overlaps HBM under knn).
__global__ __launch_bounds__(256) void knn_all_kernel(
    const float* __restrict__ xyz0, const float* __restrict__ xyz1,
    const float* __restrict__ xyz2, const float* __restrict__ xyz3,
    const float* __restrict__ xyz4, const float* __restrict__ f0,
    float* __restrict__ out,
    f32x4* pw0, f32x4* pw1, f32x4* pw2, f32x4* pw3) {
    __shared__ float lds[(256 + 1) * 4 * 4];  // 4 segs x (S4max+1) x {x,y,z,|b|2}
    int bid = blockIdx.x;
    if (bid >= 1360) {  // f0 copy: 8-channel chunk, nontemporal streaming
        bid -= 1360;
        const int b = bid >> 3;
        const int c0 = (bid & 7) * 8;
        const f32x4* src = reinterpret_cast<const f32x4*>(f0 + ((size_t)b * 64 + c0) * 4096);
        f32x4* dst = reinterpret_cast<f32x4*>(out + ((size_t)b * 1984 + c0) * 4096);
        for (int i = threadIdx.x; i < 8 * 1024; i += 256) {
            __builtin_nontemporal_store(__builtin_nontemporal_load(src + i), dst + i);
        }
        return;
    }
    int S, logS4;
    const float *xf, *xc;
    f32x4* po;
    if (bid < 1024)      { S = 1024; logS4 = 8; xf = xyz0; xc = xyz1; po = pw3; }
    else if (bid < 1280) { bid -= 1024; S = 256; logS4 = 6; xf = xyz1; xc = xyz2; po = pw2; }
    else if (bid < 1344) { bid -= 1280; S = 64;  logS4 = 4; xf = xyz2; xc = xyz3; po = pw1; }
    else                 { bid -= 1344; S = 16;  logS4 = 2; xf = xyz3; xc = xyz4; po = pw0; }
    const int N = S << 2;
    const int lognb = logS4 - 2;              // nb = N/64 = S/16
    const int b = bid >> lognb;
    const int nblk = bid & ((1 << lognb) - 1);
    const int S4 = S >> 2;

    const float* cbase = xc + (size_t)b * S * 3;
    for (int j = threadIdx.x; j < S; j += 256) {
        float x = cbase[j * 3 + 0], y = cbase[j * 3 + 1], z = cbase[j * 3 + 2];
        int seg = j >> logS4, jj = j & (S4 - 1);
        float* p = lds + (size_t)(seg * (S4 + 1) + jj) * 4;
        p[0] = x; p[1] = y; p[2] = z; p[3] = x * x + y * y + z * z;
    }
    __syncthreads();
    const int t = threadIdx.x;
    const int sub = t & 3;
    const int n = nblk * 64 + (t >> 2);
    const float* fp = xf + ((size_t)b * N + n) * 3;
    const float ax = fp[0], ay = fp[1], az = fp[2];
    const float an2 = ax * ax + ay * ay + az * az;
    float d0 = 1e30f, d1 = 1e30f, d2 = 1e30f;
    int i0 = -1, i1 = -1, i2 = -1;
    const f32x4* seg4 = reinterpret_cast<const f32x4*>(lds) + sub * (S4 + 1);
    const int jbase = sub * S4;
#pragma unroll 4
    for (int k = 0; k < S4; ++k) {
        f32x4 c = seg4[k];
        float d = an2 + c[3] - 2.0f * (ax * c[0] + ay * c[1] + az * c[2]);
        int j = jbase + k;
        if (d < d2) {  // ascending j: strict < keeps earliest index on ties
            if (d < d1) {
                d2 = d1; i2 = i1;
                if (d < d0) { d1 = d0; i1 = i0; d0 = d; i0 = j; }
                else        { d1 = d;  i1 = j; }
            } else { d2 = d; i2 = j; }
        }
    }
#pragma unroll
    for (int r = 1; r <= 2; r <<= 1) {
        float e0 = __shfl_xor(d0, r), e1 = __shfl_xor(d1, r), e2 = __shfl_xor(d2, r);
        int   j0 = __shfl_xor(i0, r), j1 = __shfl_xor(i1, r), j2 = __shfl_xor(i2, r);
        float ed[3] = {e0, e1, e2};
        int   ej[3] = {j0, j1, j2};
#pragma unroll
        for (int m = 0; m < 3; ++m) {
            float d = ed[m]; int j = ej[m];
            if (d < d0 || (d == d0 && j < i0)) {
                d2 = d1; i2 = i1; d1 = d0; i1 = i0; d0 = d; i0 = j;
            } else if (d < d1 || (d == d1 && j < i1)) {
                d2 = d1; i2 = i1; d1 = d; i1 = j;
            } else if (d < d2 || (d == d2 && j < i2)) {
                d2 = d; i2 = j;
            }
        }
    }
    if (sub == 0) {
        float w0_ = 1.0f / (d0 + 1e-8f);
        float w1_ = 1.0f / (d1 + 1e-8f);
        float w2_ = 1.0f / (d2 + 1e-8f);
        float inv = 1.0f / (w0_ + w1_ + w2_);
        unsigned packed = (unsigned)i0 | ((unsigned)i1 << 10) | ((unsigned)i2 << 20);
        f32x4 pw = {__uint_as_float(packed), w0_ * inv, w1_ * inv, w2_ * inv};
        po[(size_t)b * N + n] = pw;
    }
}

// ===================== decode mega-kernel =====================
// Block = (batch, 4-channel chunk). Expand level-by-level in LDS (one f32x4
// plane per level), final interp (pw3) streamed to d_out (nontemporal).
// LDS union, 20 KB -> 8 blocks/CU (32 waves):
//   s3 = buf[0..1024)    s2 = buf[1024..1280)
//   s1 = buf[0..64) alias   s0 = buf[64..80) alias

template <int P>
__device__ __forceinline__ void copy_plane(const float* __restrict__ src_rows,
                                           f32x4* dst, int t) {
    constexpr int P4 = P / 4;
    const f32x4* src = reinterpret_cast<const f32x4*>(src_rows);
    float* df = reinterpret_cast<float*>(dst);
    for (int e = t; e < 4 * P4; e += 256) {
        int c = e / P4;           // channel 0..3
        int s4 = e & (P4 - 1);
        f32x4 v = src[c * P4 + s4];
        int base = ((s4 * 4) << 2) + c;
        df[base + 0] = v[0]; df[base + 4] = v[1];
        df[base + 8] = v[2]; df[base + 12] = v[3];
    }
}

template <int PD, int PS>
__device__ __forceinline__ void expand(const f32x4* src, f32x4* dst,
                                       const f32x4* __restrict__ pwL,
                                       int b, int t) {
    for (int s = t; s < PD; s += 256) {
        f32x4 pw = pwL[(size_t)b * PD + s];
        int i0, i1, i2; unpack_pw(pw, i0, i1, i2);
        dst[s] = pw[1] * src[i0] + pw[2] * src[i1] + pw[3] * src[i2];
    }
}

__global__ __launch_bounds__(256, 8) void decode_kernel(
    const float* __restrict__ f1, const float* __restrict__ f2,
    const float* __restrict__ f3, const float* __restrict__ f4,
    const f32x4* __restrict__ pw0, const f32x4* __restrict__ pw1,
    const f32x4* __restrict__ pw2, const f32x4* __restrict__ pw3,
    float* __restrict__ out) {
    __shared__ f32x4 buf[1280];  // 20 KB
    f32x4* s3 = buf;
    f32x4* s2 = buf + 1024;
    f32x4* s1 = buf;       // alias (dead before s3 written)
    f32x4* s0 = buf + 64;  // alias
    const int b = blockIdx.x;
    // heavy-first: y=0 -> deepest chunk
    const int cx = (479 - blockIdx.y) * 4;  // [0,1920)
    const int t = threadIdx.x;
    float* outb = out + ((size_t)b * 1984 + 64 + cx) * 4096;

    if (cx < 128) {          // depth 1: source f1
        copy_plane<1024>(f1 + ((size_t)b * 128 + cx) * 1024, s3, t);
        __syncthreads();
    } else if (cx < 384) {   // depth 2: source f2
        copy_plane<256>(f2 + ((size_t)b * 256 + (cx - 128)) * 256, s2, t);
        __syncthreads();
        expand<1024, 256>(s2, s3, pw2, b, t);
        __syncthreads();
    } else if (cx < 896) {   // depth 3: source f3
        copy_plane<64>(f3 + ((size_t)b * 512 + (cx - 384)) * 64, s1, t);
        __syncthreads();
        expand<256, 64>(s1, s2, pw1, b, t);
        __syncthreads();
        expand<1024, 256>(s2, s3, pw2, b, t);
        __syncthreads();
    } else {                 // depth 4: source f4
        copy_plane<16>(f4 + ((size_t)b * 1024 + (cx - 896)) * 16, s0, t);
        __syncthreads();
        expand<64, 16>(s0, s1, pw0, b, t);   // s0 (buf+64) -> s1 (buf+0)
        __syncthreads();
        expand<256, 64>(s1, s2, pw1, b, t);
        __syncthreads();
        expand<1024, 256>(s2, s3, pw2, b, t);
        __syncthreads();
    }
    // final: 4096 fine points via pw3; f32x4 nontemporal stores along n
    const f32x4* pwF = pw3 + (size_t)b * 4096;
#pragma unroll 2
    for (int it = 0; it < 4; ++it) {
        const int n0 = (it * 256 + t) * 4;
        f32x4 v[4];
#pragma unroll
        for (int q = 0; q < 4; ++q) {
            f32x4 pw = pwF[n0 + q];
            int i0, i1, i2; unpack_pw(pw, i0, i1, i2);
            v[q] = pw[1] * s3[i0] + pw[2] * s3[i1] + pw[3] * s3[i2];
        }
#pragma unroll
        for (int j = 0; j < 4; ++j) {
            f32x4 st = {v[0][j], v[1][j], v[2][j], v[3][j]};
            __builtin_nontemporal_store(st, reinterpret_cast<f32x4*>(outb + (size_t)j * 4096 + n0));
        }
    }
}

extern "C" void kernel_launch(void* const* d_in, const int* in_sizes, int n_in,
                              void* d_out, int out_size, void* d_ws, size_t ws_size,
                              hipStream_t stream) {
    static const int xyzSz[5] = {16 * 4096 * 3, 16 * 1024 * 3, 16 * 256 * 3,
                                 16 * 64 * 3, 16 * 16 * 3};
    static const int fSz[5] = {16 * 64 * 4096, 16 * 128 * 1024, 16 * 256 * 256,
                               16 * 512 * 64, 16 * 1024 * 16};
    const float* xyz[5] = {nullptr, nullptr, nullptr, nullptr, nullptr};
    const float* f[5] = {nullptr, nullptr, nullptr, nullptr, nullptr};
    for (int i = 0; i < n_in; ++i) {
        for (int j = 0; j < 5; ++j) {
            if (in_sizes[i] == xyzSz[j] && !xyz[j]) { xyz[j] = (const float*)d_in[i]; goto next; }
            if (in_sizes[i] == fSz[j] && !f[j])     { f[j] = (const float*)d_in[i];  goto next; }
        }
    next:;
    }

    // ws: packed idx+w per stage (1.34 MB total, L2-resident)
    char* ws = (char*)d_ws;
    f32x4* pw3 = (f32x4*)(ws);                       // 16*4096*16 = 1 MiB
    f32x4* pw2 = (f32x4*)(ws + (1u << 20));          // 256 KiB
    f32x4* pw1 = (f32x4*)(ws + (1u << 20) + 262144u);   // 64 KiB
    f32x4* pw0 = (f32x4*)(ws + (1u << 20) + 327680u);   // 16 KiB

    knn_all_kernel<<<1488, 256, 0, stream>>>(
        xyz[0], xyz[1], xyz[2], xyz[3], xyz[4], f[0], (float*)d_out,
        pw0, pw1, pw2, pw3);

    decode_kernel<<<dim3(B, 480), 256, 0, stream>>>(
        f[1], f[2], f[3], f[4], pw0, pw1, pw2, pw3, (float*)d_out);
}

// Round 6
// 127.472 us; speedup vs baseline: 1.0604x; 1.0604x over previous
//
#include <hip/hip_runtime.h>

#define B 16
typedef float f32x4 __attribute__((ext_vector_type(4)));

// pw layout: .x = bit-packed indices (i0 | i1<<10 | i2<<20), .y/.z/.w = weights
__device__ __forceinline__ void unpack_pw(const f32x4 pw, int& i0, int& i1, int& i2) {
    unsigned p = __float_as_uint(pw[0]);
    i0 = p & 1023; i1 = (p >> 10) & 1023; i2 = p >> 20;
}

// ===================== fused 4-stage 3-NN + f0 copy =====================
// Blocks [0,1024): stage3; [1024,1280): stage2; [1280,1344): stage1;
// [1344,1360): stage0; [1360,1488): f0 -> out copy (overlaps HBM under knn).
__global__ __launch_bounds__(256) void knn_all_kernel(
    const float* __restrict__ xyz0, const float* __restrict__ xyz1,
    const float* __restrict__ xyz2, const float* __restrict__ xyz3,
    const float* __restrict__ xyz4, const float* __restrict__ f0,
    float* __restrict__ out,
    f32x4* pw0, f32x4* pw1, f32x4* pw2, f32x4* pw3) {
    __shared__ float lds[(256 + 1) * 4 * 4];  // 4 segs x (S4max+1) x {x,y,z,|b|2}
    int bid = blockIdx.x;
    if (bid >= 1360) {  // f0 copy: 8-channel chunk, nontemporal streaming
        bid -= 1360;
        const int b = bid >> 3;
        const int c0 = (bid & 7) * 8;
        const f32x4* src = reinterpret_cast<const f32x4*>(f0 + ((size_t)b * 64 + c0) * 4096);
        f32x4* dst = reinterpret_cast<f32x4*>(out + ((size_t)b * 1984 + c0) * 4096);
        for (int i = threadIdx.x; i < 8 * 1024; i += 256) {
            __builtin_nontemporal_store(__builtin_nontemporal_load(src + i), dst + i);
        }
        return;
    }
    int S, logS4;
    const float *xf, *xc;
    f32x4* po;
    if (bid < 1024)      { S = 1024; logS4 = 8; xf = xyz0; xc = xyz1; po = pw3; }
    else if (bid < 1280) { bid -= 1024; S = 256; logS4 = 6; xf = xyz1; xc = xyz2; po = pw2; }
    else if (bid < 1344) { bid -= 1280; S = 64;  logS4 = 4; xf = xyz2; xc = xyz3; po = pw1; }
    else                 { bid -= 1344; S = 16;  logS4 = 2; xf = xyz3; xc = xyz4; po = pw0; }
    const int N = S << 2;
    const int lognb = logS4 - 2;              // nb = N/64 = S/16
    const int b = bid >> lognb;
    const int nblk = bid & ((1 << lognb) - 1);
    const int S4 = S >> 2;

    const float* cbase = xc + (size_t)b * S * 3;
    for (int j = threadIdx.x; j < S; j += 256) {
        float x = cbase[j * 3 + 0], y = cbase[j * 3 + 1], z = cbase[j * 3 + 2];
        int seg = j >> logS4, jj = j & (S4 - 1);
        float* p = lds + (size_t)(seg * (S4 + 1) + jj) * 4;
        p[0] = x; p[1] = y; p[2] = z; p[3] = x * x + y * y + z * z;
    }
    __syncthreads();
    const int t = threadIdx.x;
    const int sub = t & 3;
    const int n = nblk * 64 + (t >> 2);
    const float* fp = xf + ((size_t)b * N + n) * 3;
    const float ax = fp[0], ay = fp[1], az = fp[2];
    const float an2 = ax * ax + ay * ay + az * az;
    float d0 = 1e30f, d1 = 1e30f, d2 = 1e30f;
    int i0 = -1, i1 = -1, i2 = -1;
    const f32x4* seg4 = reinterpret_cast<const f32x4*>(lds) + sub * (S4 + 1);
    const int jbase = sub * S4;
#pragma unroll 4
    for (int k = 0; k < S4; ++k) {
        f32x4 c = seg4[k];
        float d = an2 + c[3] - 2.0f * (ax * c[0] + ay * c[1] + az * c[2]);
        int j = jbase + k;
        if (d < d2) {  // ascending j: strict < keeps earliest index on ties
            if (d < d1) {
                d2 = d1; i2 = i1;
                if (d < d0) { d1 = d0; i1 = i0; d0 = d; i0 = j; }
                else        { d1 = d;  i1 = j; }
            } else { d2 = d; i2 = j; }
        }
    }
#pragma unroll
    for (int r = 1; r <= 2; r <<= 1) {
        float e0 = __shfl_xor(d0, r), e1 = __shfl_xor(d1, r), e2 = __shfl_xor(d2, r);
        int   j0 = __shfl_xor(i0, r), j1 = __shfl_xor(i1, r), j2 = __shfl_xor(i2, r);
        float ed[3] = {e0, e1, e2};
        int   ej[3] = {j0, j1, j2};
#pragma unroll
        for (int m = 0; m < 3; ++m) {
            float d = ed[m]; int j = ej[m];
            if (d < d0 || (d == d0 && j < i0)) {
                d2 = d1; i2 = i1; d1 = d0; i1 = i0; d0 = d; i0 = j;
            } else if (d < d1 || (d == d1 && j < i1)) {
                d2 = d1; i2 = i1; d1 = d; i1 = j;
            } else if (d < d2 || (d == d2 && j < i2)) {
                d2 = d; i2 = j;
            }
        }
    }
    if (sub == 0) {
        float w0_ = 1.0f / (d0 + 1e-8f);
        float w1_ = 1.0f / (d1 + 1e-8f);
        float w2_ = 1.0f / (d2 + 1e-8f);
        float inv = 1.0f / (w0_ + w1_ + w2_);
        unsigned packed = (unsigned)i0 | ((unsigned)i1 << 10) | ((unsigned)i2 << 20);
        f32x4 pw = {__uint_as_float(packed), w0_ * inv, w1_ * inv, w2_ * inv};
        po[(size_t)b * N + n] = pw;
    }
}

// ===================== decode mega-kernel =====================
// Block = (batch, 8-channel chunk). Expand level-by-level in LDS (f32x4
// planes, 4 channels each), final interp (pw3) streamed to d_out (nt stores).
// LDS union, exactly 40 KB -> 4 blocks/CU:
//   s3 = buf[0..2048)    s2 = buf[2048..2560)
//   s1 = buf[0..128) alias   s0 = buf[128..160) alias

template <int P>
__device__ __forceinline__ void copy_planes(const float* __restrict__ src_rows,
                                            f32x4* dst, int t) {
    constexpr int P4 = P / 4;
    const f32x4* src = reinterpret_cast<const f32x4*>(src_rows);
    float* df = reinterpret_cast<float*>(dst);
    for (int e = t; e < 8 * P4; e += 256) {
        int c = e / P4;
        int s4 = e & (P4 - 1);
        f32x4 v = src[c * P4 + s4];
        int base = (((c >> 2) * P + s4 * 4) << 2) + (c & 3);
        df[base + 0] = v[0]; df[base + 4] = v[1];
        df[base + 8] = v[2]; df[base + 12] = v[3];
    }
}

template <int PD, int PS>
__device__ __forceinline__ void expand(const f32x4* src, f32x4* dst,
                                       const f32x4* __restrict__ pwL,
                                       int b, int t) {
    for (int e = t; e < 2 * PD; e += 256) {
        int p = (e >= PD) ? 1 : 0;
        int s = e - p * PD;
        f32x4 pw = pwL[(size_t)b * PD + s];
        int i0, i1, i2; unpack_pw(pw, i0, i1, i2);
        const f32x4* sp = src + p * PS;
        dst[e] = pw[1] * sp[i0] + pw[2] * sp[i1] + pw[3] * sp[i2];
    }
}

__global__ __launch_bounds__(256) void decode_kernel(
    const float* __restrict__ f1, const float* __restrict__ f2,
    const float* __restrict__ f3, const float* __restrict__ f4,
    const f32x4* __restrict__ pw0, const f32x4* __restrict__ pw1,
    const f32x4* __restrict__ pw2, const f32x4* __restrict__ pw3,
    float* __restrict__ out) {
    __shared__ f32x4 buf[2560];  // 40 KB exactly
    f32x4* s3 = buf;
    f32x4* s2 = buf + 2048;
    f32x4* s1 = buf;        // alias (dead before s3 written)
    f32x4* s0 = buf + 128;  // alias
    const int b = blockIdx.x;
    // Interleaved schedule: chunks 0..239 (cx = c*8). depth4 = c in [112,240),
    // shallow = c in [0,112). First the 16 deepest, then alternate d4/shallow
    // so every CU hosts a mix of prologue-bound and streaming blocks.
    const int y = blockIdx.y;
    int c;
    if (y < 16) c = 224 + y;
    else {
        int z = y - 16;
        c = (z & 1) ? (z >> 1) : 112 + (z >> 1);
    }
    const int cx = c * 8;  // [0,1920)
    const int t = threadIdx.x;
    float* outb = out + ((size_t)b * 1984 + 64 + cx) * 4096;

    if (cx < 128) {          // depth 1: source f1
        copy_planes<1024>(f1 + ((size_t)b * 128 + cx) * 1024, s3, t);
        __syncthreads();
    } else if (cx < 384) {   // depth 2: source f2
        copy_planes<256>(f2 + ((size_t)b * 256 + (cx - 128)) * 256, s2, t);
        __syncthreads();
        expand<1024, 256>(s2, s3, pw2, b, t);
        __syncthreads();
    } else if (cx < 896) {   // depth 3: source f3
        copy_planes<64>(f3 + ((size_t)b * 512 + (cx - 384)) * 64, s1, t);
        __syncthreads();
        expand<256, 64>(s1, s2, pw1, b, t);
        __syncthreads();
        expand<1024, 256>(s2, s3, pw2, b, t);
        __syncthreads();
    } else {                 // depth 4: source f4
        copy_planes<16>(f4 + ((size_t)b * 1024 + (cx - 896)) * 16, s0, t);
        __syncthreads();
        expand<64, 16>(s0, s1, pw0, b, t);   // s0 (buf+128) -> s1 (buf+0)
        __syncthreads();
        expand<256, 64>(s1, s2, pw1, b, t);
        __syncthreads();
        expand<1024, 256>(s2, s3, pw2, b, t);
        __syncthreads();
    }
    // final: 4096 fine points via pw3; f32x4 nontemporal stores along n
    const f32x4* pwF = pw3 + (size_t)b * 4096;
#pragma unroll 2
    for (int it = 0; it < 4; ++it) {
        const int n0 = (it * 256 + t) * 4;
        f32x4 pwv[4];
#pragma unroll
        for (int q = 0; q < 4; ++q) pwv[q] = pwF[n0 + q];
#pragma unroll
        for (int p = 0; p < 2; ++p) {
            const f32x4* pl = s3 + p * 1024;
            f32x4 v[4];
#pragma unroll
            for (int q = 0; q < 4; ++q) {
                int i0, i1, i2; unpack_pw(pwv[q], i0, i1, i2);
                v[q] = pwv[q][1] * pl[i0] + pwv[q][2] * pl[i1] + pwv[q][3] * pl[i2];
            }
            float* ob = outb + (size_t)(p * 4) * 4096 + n0;
#pragma unroll
            for (int j = 0; j < 4; ++j) {
                f32x4 st = {v[0][j], v[1][j], v[2][j], v[3][j]};
                __builtin_nontemporal_store(st, reinterpret_cast<f32x4*>(ob + (size_t)j * 4096));
            }
        }
    }
}

extern "C" void kernel_launch(void* const* d_in, const int* in_sizes, int n_in,
                              void* d_out, int out_size, void* d_ws, size_t ws_size,
                              hipStream_t stream) {
    static const int xyzSz[5] = {16 * 4096 * 3, 16 * 1024 * 3, 16 * 256 * 3,
                                 16 * 64 * 3, 16 * 16 * 3};
    static const int fSz[5] = {16 * 64 * 4096, 16 * 128 * 1024, 16 * 256 * 256,
                               16 * 512 * 64, 16 * 1024 * 16};
    const float* xyz[5] = {nullptr, nullptr, nullptr, nullptr, nullptr};
    const float* f[5] = {nullptr, nullptr, nullptr, nullptr, nullptr};
    for (int i = 0; i < n_in; ++i) {
        for (int j = 0; j < 5; ++j) {
            if (in_sizes[i] == xyzSz[j] && !xyz[j]) { xyz[j] = (const float*)d_in[i]; goto next; }
            if (in_sizes[i] == fSz[j] && !f[j])     { f[j] = (const float*)d_in[i];  goto next; }
        }
    next:;
    }

    // ws: packed idx+w per stage (1.34 MB total, L2-resident)
    char* ws = (char*)d_ws;
    f32x4* pw3 = (f32x4*)(ws);                       // 1 MiB
    f32x4* pw2 = (f32x4*)(ws + (1u << 20));          // 256 KiB
    f32x4* pw1 = (f32x4*)(ws + (1u << 20) + 262144u);   // 64 KiB
    f32x4* pw0 = (f32x4*)(ws + (1u << 20) + 327680u);   // 16 KiB

    knn_all_kernel<<<1488, 256, 0, stream>>>(
        xyz[0], xyz[1], xyz[2], xyz[3], xyz[4], f[0], (float*)d_out,
        pw0, pw1, pw2, pw3);

    decode_kernel<<<dim3(B, 240), 256, 0, stream>>>(
        f[1], f[2], f[3], f[4], pw0, pw1, pw2, pw3, (float*)d_out);
}